// Round 1
// baseline (257.633 us; speedup 1.0000x reference)
//
#include <hip/hip_runtime.h>

#define TS 512  // timesteps
#define DD 64   // input dim
#define HH 32   // hidden dim

__device__ __forceinline__ float fast_sigmoid(float a) {
    return __builtin_amdgcn_rcpf(1.0f + __expf(-a));
}

// One wave (64 lanes) per batch element.
// lane = s*32 + h:  s in {0,1} = half-index for dot-product split, h = hidden index.
// Each lane computes partial dot products over its half of D (32 of 64) and of H
// (16 of 32), halves combined via shfl_xor(32). Gate math is computed redundantly
// in both halves (keeps h_own replicated; no extra broadcast needed).
__global__ __launch_bounds__(64, 1) void gru_fused(
    const float* __restrict__ x,
    const float* __restrict__ Wih,
    const float* __restrict__ Whh,
    const float* __restrict__ bih,
    const float* __restrict__ bhh,
    const float* __restrict__ Wfc,
    const float* __restrict__ bfc,
    float* __restrict__ out)
{
    __shared__ __align__(16) float xs[4][DD];  // rotating x staging slots
    __shared__ __align__(16) float hs[HH];     // h broadcast buffer

    const int b    = blockIdx.x;
    const int lane = threadIdx.x;
    const int s    = lane >> 5;   // 0/1: which half of the dot
    const int h    = lane & 31;   // hidden index owned by this lane

    // ---- W_ih rows (gates r,z,n), this lane's d-half: 96 regs ----
    float wr[32], wz[32], wn[32];
    {
        const float4* pr = reinterpret_cast<const float4*>(Wih + (0 * HH + h) * DD + s * 32);
        const float4* pz = reinterpret_cast<const float4*>(Wih + (1 * HH + h) * DD + s * 32);
        const float4* pn = reinterpret_cast<const float4*>(Wih + (2 * HH + h) * DD + s * 32);
#pragma unroll
        for (int k = 0; k < 8; ++k) {
            float4 a = pr[k]; wr[4*k]=a.x; wr[4*k+1]=a.y; wr[4*k+2]=a.z; wr[4*k+3]=a.w;
            float4 c = pz[k]; wz[4*k]=c.x; wz[4*k+1]=c.y; wz[4*k+2]=c.z; wz[4*k+3]=c.w;
            float4 e = pn[k]; wn[4*k]=e.x; wn[4*k+1]=e.y; wn[4*k+2]=e.z; wn[4*k+3]=e.w;
        }
    }
    // ---- W_hh rows, this lane's j-half: 48 regs ----
    float ur[16], uz[16], un[16];
    {
        const float4* pr = reinterpret_cast<const float4*>(Whh + (0 * HH + h) * HH + s * 16);
        const float4* pz = reinterpret_cast<const float4*>(Whh + (1 * HH + h) * HH + s * 16);
        const float4* pn = reinterpret_cast<const float4*>(Whh + (2 * HH + h) * HH + s * 16);
#pragma unroll
        for (int k = 0; k < 4; ++k) {
            float4 a = pr[k]; ur[4*k]=a.x; ur[4*k+1]=a.y; ur[4*k+2]=a.z; ur[4*k+3]=a.w;
            float4 c = pz[k]; uz[4*k]=c.x; uz[4*k+1]=c.y; uz[4*k+2]=c.z; uz[4*k+3]=c.w;
            float4 e = pn[k]; un[4*k]=e.x; un[4*k+1]=e.y; un[4*k+2]=e.z; un[4*k+3]=e.w;
        }
    }

    const float br  = bih[h]          + bhh[h];
    const float bz  = bih[HH + h]     + bhh[HH + h];
    const float bxn = bih[2 * HH + h];
    const float bhn = bhh[2 * HH + h];
    const float wfc = Wfc[h];
    const float bf0 = bfc[0];

    const float* xrow = x + (size_t)b * TS * DD;

    // ---- prologue: fill slots 0..2, put 3 loads in flight (steps 3,4,5) ----
    float p0 = xrow[0 * DD + lane];
    float p1 = xrow[1 * DD + lane];
    float p2 = xrow[2 * DD + lane];
    float ra = xrow[3 * DD + lane];
    float rb = xrow[4 * DD + lane];
    float rc = xrow[5 * DD + lane];
    xs[0][lane] = p0;
    xs[1][lane] = p1;
    xs[2][lane] = p2;

    float h_own = 0.0f;
    float hv[16];
#pragma unroll
    for (int k = 0; k < 16; ++k) hv[k] = 0.0f;

    for (int t = 0; t < TS; ++t) {
        // stage step t+3 (loaded 3 iterations ago -> no vmcnt stall)
        xs[(t + 3) & 3][lane] = ra;
        ra = rb; rb = rc;
        int tf = t + 6; if (tf > TS - 1) tf = TS - 1;   // harmless tail re-read
        rc = xrow[tf * DD + lane];

        // ---- xg partial dots (this lane's 32 of 64 d's), x via LDS broadcast ----
        const float4* xp = reinterpret_cast<const float4*>(&xs[t & 3][s * 32]);
        float ar = 0.f, az = 0.f, an = 0.f;
#pragma unroll
        for (int k = 0; k < 8; ++k) {
            float4 v = xp[k];
            ar = fmaf(wr[4*k  ], v.x, ar);
            az = fmaf(wz[4*k  ], v.x, az);
            an = fmaf(wn[4*k  ], v.x, an);
            ar = fmaf(wr[4*k+1], v.y, ar);
            az = fmaf(wz[4*k+1], v.y, az);
            an = fmaf(wn[4*k+1], v.y, an);
            ar = fmaf(wr[4*k+2], v.z, ar);
            az = fmaf(wz[4*k+2], v.z, az);
            an = fmaf(wn[4*k+2], v.z, an);
            ar = fmaf(wr[4*k+3], v.w, ar);
            az = fmaf(wz[4*k+3], v.w, az);
            an = fmaf(wn[4*k+3], v.w, an);
        }
        // ---- gh partial dots (this lane's 16 of 32 j's) ----
        float gr = 0.f, gz = 0.f, gn = 0.f;
#pragma unroll
        for (int k = 0; k < 16; ++k) {
            gr = fmaf(ur[k], hv[k], gr);
            gz = fmaf(uz[k], hv[k], gz);
            gn = fmaf(un[k], hv[k], gn);
        }

        // ---- combine halves ----
        float tr = ar + gr;  tr += __shfl_xor(tr, 32);
        float tz = az + gz;  tz += __shfl_xor(tz, 32);
        float txn = an + __shfl_xor(an, 32);
        float tgn = gn + __shfl_xor(gn, 32);

        // ---- gates (redundant in both halves; identical results) ----
        float r = fast_sigmoid(tr + br);
        float z = fast_sigmoid(tz + bz);
        float npre = txn + bxn + r * (tgn + bhn);
        npre = fminf(fmaxf(npre, -30.f), 30.f);           // avoid inf/inf NaN
        float e2 = __expf(-2.f * npre);
        float n = (1.f - e2) * __builtin_amdgcn_rcpf(1.f + e2);
        h_own = n + z * (h_own - n);

        // ---- share h across lanes (wave-synchronous; block == 1 wave) ----
        hs[h] = h_own;   // both halves write identical value
        __builtin_amdgcn_wave_barrier();
        const float4* hp = reinterpret_cast<const float4*>(&hs[s * 16]);
#pragma unroll
        for (int k = 0; k < 4; ++k) {
            float4 q = hp[k];
            hv[4*k]=q.x; hv[4*k+1]=q.y; hv[4*k+2]=q.z; hv[4*k+3]=q.w;
        }
    }

    // ---- final fc: out[b] = dot(h, W_fc) + b_fc (each h counted twice) ----
    float v = h_own * wfc;
#pragma unroll
    for (int off = 32; off >= 1; off >>= 1) v += __shfl_xor(v, off);
    if (lane == 0) out[b] = 0.5f * v + bf0;
}

extern "C" void kernel_launch(void* const* d_in, const int* in_sizes, int n_in,
                              void* d_out, int out_size, void* d_ws, size_t ws_size,
                              hipStream_t stream) {
    const float* x    = (const float*)d_in[0];
    const float* Wih  = (const float*)d_in[1];
    const float* Whh  = (const float*)d_in[2];
    const float* bih  = (const float*)d_in[3];
    const float* bhh  = (const float*)d_in[4];
    const float* Wfc  = (const float*)d_in[5];
    const float* bfc  = (const float*)d_in[6];
    float* out = (float*)d_out;

    const int B = in_sizes[0] / (TS * DD);   // 1024
    gru_fused<<<dim3(B), dim3(64), 0, stream>>>(x, Wih, Whh, bih, bhh, Wfc, bfc, out);
}

// Round 2
// 190.519 us; speedup vs baseline: 1.3523x; 1.3523x over previous
//
#include <hip/hip_runtime.h>

#define TS 512  // timesteps
#define DD 64   // input dim
#define HH 32   // hidden dim

typedef _Float16 half2v __attribute__((ext_vector_type(2)));

__device__ __forceinline__ float fdot2(half2v a, half2v b, float c) {
#if __has_builtin(__builtin_amdgcn_fdot2)
    return __builtin_amdgcn_fdot2(a, b, c, false);
#else
    return fmaf((float)a[0], (float)b[0], fmaf((float)a[1], (float)b[1], c));
#endif
}

__device__ __forceinline__ float fast_sigmoid(float a) {
    return __builtin_amdgcn_rcpf(1.0f + __expf(-a));
}

// One wave (64 lanes) per batch element.
// lane = s*32 + h:  s = half-index for dot split, h = hidden index.
// Weights held as packed fp16 pairs in VGPRs (72 regs); x and h pass through
// LDS as fp16; all accumulation and the recurrent state h are fp32.
__global__ __launch_bounds__(64, 1) void gru_fused(
    const float* __restrict__ x,
    const float* __restrict__ Wih,
    const float* __restrict__ Whh,
    const float* __restrict__ bih,
    const float* __restrict__ bhh,
    const float* __restrict__ Wfc,
    const float* __restrict__ bfc,
    float* __restrict__ out)
{
    __shared__ __align__(16) _Float16 xs16[4][DD];  // rotating x staging (fp16)
    __shared__ __align__(16) _Float16 hs16[HH];     // h broadcast (fp16)

    const int b    = blockIdx.x;
    const int lane = threadIdx.x;
    const int s    = lane >> 5;   // 0/1: which half of the dot
    const int h    = lane & 31;   // hidden index owned by this lane

    // ---- W_ih rows (r,z,n), this lane's d-half: 48 packed regs ----
    half2v wr2[16], wz2[16], wn2[16];
    {
        const float4* pr = reinterpret_cast<const float4*>(Wih + (0 * HH + h) * DD + s * 32);
        const float4* pz = reinterpret_cast<const float4*>(Wih + (1 * HH + h) * DD + s * 32);
        const float4* pn = reinterpret_cast<const float4*>(Wih + (2 * HH + h) * DD + s * 32);
#pragma unroll
        for (int k = 0; k < 8; ++k) {
            float4 a = pr[k];
            wr2[2*k]   = half2v{(_Float16)a.x, (_Float16)a.y};
            wr2[2*k+1] = half2v{(_Float16)a.z, (_Float16)a.w};
            float4 c = pz[k];
            wz2[2*k]   = half2v{(_Float16)c.x, (_Float16)c.y};
            wz2[2*k+1] = half2v{(_Float16)c.z, (_Float16)c.w};
            float4 e = pn[k];
            wn2[2*k]   = half2v{(_Float16)e.x, (_Float16)e.y};
            wn2[2*k+1] = half2v{(_Float16)e.z, (_Float16)e.w};
        }
    }
    // ---- W_hh rows, this lane's j-half: 24 packed regs ----
    half2v ur2[8], uz2[8], un2[8];
    {
        const float4* pr = reinterpret_cast<const float4*>(Whh + (0 * HH + h) * HH + s * 16);
        const float4* pz = reinterpret_cast<const float4*>(Whh + (1 * HH + h) * HH + s * 16);
        const float4* pn = reinterpret_cast<const float4*>(Whh + (2 * HH + h) * HH + s * 16);
#pragma unroll
        for (int k = 0; k < 4; ++k) {
            float4 a = pr[k];
            ur2[2*k]   = half2v{(_Float16)a.x, (_Float16)a.y};
            ur2[2*k+1] = half2v{(_Float16)a.z, (_Float16)a.w};
            float4 c = pz[k];
            uz2[2*k]   = half2v{(_Float16)c.x, (_Float16)c.y};
            uz2[2*k+1] = half2v{(_Float16)c.z, (_Float16)c.w};
            float4 e = pn[k];
            un2[2*k]   = half2v{(_Float16)e.x, (_Float16)e.y};
            un2[2*k+1] = half2v{(_Float16)e.z, (_Float16)e.w};
        }
    }

    const float br  = bih[h]          + bhh[h];
    const float bz  = bih[HH + h]     + bhh[HH + h];
    const float bxn = bih[2 * HH + h];
    const float bhn = bhh[2 * HH + h];
    const float wfc = Wfc[h];
    const float bf0 = bfc[0];

    const float* xrow = x + (size_t)b * TS * DD;

    // ---- prologue: stage slots 0..2, keep 3 loads in flight ----
    float p0 = xrow[0 * DD + lane];
    float p1 = xrow[1 * DD + lane];
    float p2 = xrow[2 * DD + lane];
    float ra = xrow[3 * DD + lane];
    float rb = xrow[4 * DD + lane];
    float rc = xrow[5 * DD + lane];
    xs16[0][lane] = (_Float16)p0;
    xs16[1][lane] = (_Float16)p1;
    xs16[2][lane] = (_Float16)p2;
    __builtin_amdgcn_wave_barrier();

    float h_own = 0.0f;
    half2v hv2[8];
#pragma unroll
    for (int k = 0; k < 8; ++k) hv2[k] = half2v{(_Float16)0.0f, (_Float16)0.0f};

    // xg partials for t=0 (x already staged)
    float ar, az, an;
    {
        const uint4* xp = reinterpret_cast<const uint4*>(&xs16[0][s * 32]);
        ar = 0.f; az = 0.f; an = 0.f;
#pragma unroll
        for (int k = 0; k < 4; ++k) {
            uint4 q = xp[k];
            half2v v0 = __builtin_bit_cast(half2v, q.x);
            half2v v1 = __builtin_bit_cast(half2v, q.y);
            half2v v2 = __builtin_bit_cast(half2v, q.z);
            half2v v3 = __builtin_bit_cast(half2v, q.w);
            ar = fdot2(wr2[4*k  ], v0, ar);
            az = fdot2(wz2[4*k  ], v0, az);
            an = fdot2(wn2[4*k  ], v0, an);
            ar = fdot2(wr2[4*k+1], v1, ar);
            az = fdot2(wz2[4*k+1], v1, az);
            an = fdot2(wn2[4*k+1], v1, an);
            ar = fdot2(wr2[4*k+2], v2, ar);
            az = fdot2(wz2[4*k+2], v2, az);
            an = fdot2(wn2[4*k+2], v2, an);
            ar = fdot2(wr2[4*k+3], v3, ar);
            az = fdot2(wz2[4*k+3], v3, az);
            an = fdot2(wn2[4*k+3], v3, an);
        }
    }

    for (int t = 0; t < TS; ++t) {
        // stage step t+3 (its load was issued 3 iterations ago)
        xs16[(t + 3) & 3][lane] = (_Float16)ra;
        ra = rb; rb = rc;
        int tf = t + 6; if (tf > TS - 1) tf = TS - 1;   // harmless tail re-read
        rc = xrow[tf * DD + lane];

        // ---- gh partial dots (this lane's 16 of 32 j's) ----
        float gr = 0.f, gz = 0.f, gn = 0.f;
#pragma unroll
        for (int k = 0; k < 8; ++k) {
            gr = fdot2(ur2[k], hv2[k], gr);
            gz = fdot2(uz2[k], hv2[k], gz);
            gn = fdot2(un2[k], hv2[k], gn);
        }

        // ---- combine halves ----
        float tr = ar + gr;  tr += __shfl_xor(tr, 32);
        float tz = az + gz;  tz += __shfl_xor(tz, 32);
        float txn = an + __shfl_xor(an, 32);
        float tgn = gn + __shfl_xor(gn, 32);

        // ---- gates (redundant in both halves; identical results) ----
        float r = fast_sigmoid(tr + br);
        float z = fast_sigmoid(tz + bz);
        float npre = txn + bxn + r * (tgn + bhn);
        npre = fminf(fmaxf(npre, -30.f), 30.f);
        float e2 = __expf(-2.f * npre);
        float n = (1.f - e2) * __builtin_amdgcn_rcpf(1.f + e2);
        h_own = n + z * (h_own - n);

        // ---- broadcast h (fp16) — wave-synchronous, block == 1 wave ----
        hs16[h] = (_Float16)h_own;
        __builtin_amdgcn_wave_barrier();
        {
            const uint4* hp = reinterpret_cast<const uint4*>(&hs16[s * 16]);
            uint4 q0 = hp[0];
            uint4 q1 = hp[1];
            hv2[0] = __builtin_bit_cast(half2v, q0.x);
            hv2[1] = __builtin_bit_cast(half2v, q0.y);
            hv2[2] = __builtin_bit_cast(half2v, q0.z);
            hv2[3] = __builtin_bit_cast(half2v, q0.w);
            hv2[4] = __builtin_bit_cast(half2v, q1.x);
            hv2[5] = __builtin_bit_cast(half2v, q1.y);
            hv2[6] = __builtin_bit_cast(half2v, q1.z);
            hv2[7] = __builtin_bit_cast(half2v, q1.w);
        }

        // ---- xg partials for step t+1 (independent; fills h-chain latency) ----
        if (t + 1 < TS) {
            const uint4* xp = reinterpret_cast<const uint4*>(&xs16[(t + 1) & 3][s * 32]);
            ar = 0.f; az = 0.f; an = 0.f;
#pragma unroll
            for (int k = 0; k < 4; ++k) {
                uint4 q = xp[k];
                half2v v0 = __builtin_bit_cast(half2v, q.x);
                half2v v1 = __builtin_bit_cast(half2v, q.y);
                half2v v2 = __builtin_bit_cast(half2v, q.z);
                half2v v3 = __builtin_bit_cast(half2v, q.w);
                ar = fdot2(wr2[4*k  ], v0, ar);
                az = fdot2(wz2[4*k  ], v0, az);
                an = fdot2(wn2[4*k  ], v0, an);
                ar = fdot2(wr2[4*k+1], v1, ar);
                az = fdot2(wz2[4*k+1], v1, az);
                an = fdot2(wn2[4*k+1], v1, an);
                ar = fdot2(wr2[4*k+2], v2, ar);
                az = fdot2(wz2[4*k+2], v2, az);
                an = fdot2(wn2[4*k+2], v2, an);
                ar = fdot2(wr2[4*k+3], v3, ar);
                az = fdot2(wz2[4*k+3], v3, az);
                an = fdot2(wn2[4*k+3], v3, an);
            }
        }
    }

    // ---- final fc: out[b] = dot(h, W_fc) + b_fc (each h counted twice) ----
    float v = h_own * wfc;
#pragma unroll
    for (int off = 32; off >= 1; off >>= 1) v += __shfl_xor(v, off);
    if (lane == 0) out[b] = 0.5f * v + bf0;
}

extern "C" void kernel_launch(void* const* d_in, const int* in_sizes, int n_in,
                              void* d_out, int out_size, void* d_ws, size_t ws_size,
                              hipStream_t stream) {
    const float* x    = (const float*)d_in[0];
    const float* Wih  = (const float*)d_in[1];
    const float* Whh  = (const float*)d_in[2];
    const float* bih  = (const float*)d_in[3];
    const float* bhh  = (const float*)d_in[4];
    const float* Wfc  = (const float*)d_in[5];
    const float* bfc  = (const float*)d_in[6];
    float* out = (float*)d_out;

    const int B = in_sizes[0] / (TS * DD);   // 1024
    gru_fused<<<dim3(B), dim3(64), 0, stream>>>(x, Wih, Whh, bih, bhh, Wfc, bfc, out);
}